// Round 5
// baseline (247.020 us; speedup 1.0000x reference)
//
#include <hip/hip_runtime.h>
#include <hip/hip_bf16.h>

#define S_LEN 2048
#define NH 32
#define D_DIM 128
#define LAST_Q 64
#define SCALE_F 0.08838834764831845f
#define QSCALE (0.08838834764831845f * 1.4426950408889634f)  // scale * log2(e)
#define RESCALE_THR 11.54f

typedef __attribute__((ext_vector_type(8))) short bf16x8;
typedef __attribute__((ext_vector_type(4))) float f32x4;
typedef unsigned long long u64;
typedef unsigned int u32;
typedef unsigned short u16;

static __device__ __forceinline__ u16 f32_bf16(float f) {
  u32 u = __float_as_uint(f);
  u32 r = (u + 0x7FFFu + ((u >> 16) & 1u)) >> 16;
  return (u16)r;
}

// ---------------- Stage 0: preconvert to PRE-SWIZZLED bf16 layouts ----------------
// kpre[h][t][p]: p in [0,1024), r=p>>4, holds K[h][t*64+r][g*8..+8) with g=(p&15)^(r&15).
// vpre[h][t][p]: d=p>>3, holds V[h][t*64+cb*8+e][d] e<8 with cb=(p&7)^(d&7).
// Linear global_load_lds of these lands in the XOR-swizzled LDS layout directly.
__global__ __launch_bounds__(256) void conv_kernel(const float* __restrict__ k,
                                                   const float* __restrict__ v,
                                                   u16* __restrict__ kpre,
                                                   u16* __restrict__ vpre) {
  int bid = blockIdx.x;
  int t = bid & 31, h = bid >> 5;
  int tid = threadIdx.x;
  int c0 = t * 64;
  __shared__ u16 Vb[64][136];
  // stage V tile rows (coalesced) -> LDS bf16
  for (int i = tid; i < 512; i += 256) {
    int r = i >> 3, s = i & 7;
    const float* srcp = v + ((size_t)(h * S_LEN + c0 + r)) * D_DIM + s * 16;
    float4 f0 = *(const float4*)(srcp);
    float4 f1 = *(const float4*)(srcp + 4);
    float4 f2 = *(const float4*)(srcp + 8);
    float4 f3 = *(const float4*)(srcp + 12);
    bf16x8 t0, t1;
    t0[0] = (short)f32_bf16(f0.x); t0[1] = (short)f32_bf16(f0.y);
    t0[2] = (short)f32_bf16(f0.z); t0[3] = (short)f32_bf16(f0.w);
    t0[4] = (short)f32_bf16(f1.x); t0[5] = (short)f32_bf16(f1.y);
    t0[6] = (short)f32_bf16(f1.z); t0[7] = (short)f32_bf16(f1.w);
    t1[0] = (short)f32_bf16(f2.x); t1[1] = (short)f32_bf16(f2.y);
    t1[2] = (short)f32_bf16(f2.z); t1[3] = (short)f32_bf16(f2.w);
    t1[4] = (short)f32_bf16(f3.x); t1[5] = (short)f32_bf16(f3.y);
    t1[6] = (short)f32_bf16(f3.z); t1[7] = (short)f32_bf16(f3.w);
    *(bf16x8*)&Vb[r][s * 16] = t0;
    *(bf16x8*)&Vb[r][s * 16 + 8] = t1;
  }
  // K: permuted 16B-group gather -> contiguous store
  u16* kp = kpre + (size_t)h * 262144 + (size_t)t * 8192;
#pragma unroll
  for (int j = 0; j < 4; ++j) {
    int p = j * 256 + tid;
    int r = p >> 4;
    int g = (p & 15) ^ (r & 15);
    const float* srcp = k + ((size_t)(h * S_LEN + c0 + r)) * D_DIM + g * 8;
    float4 a = *(const float4*)srcp;
    float4 b = *(const float4*)(srcp + 4);
    bf16x8 o;
    o[0] = (short)f32_bf16(a.x); o[1] = (short)f32_bf16(a.y);
    o[2] = (short)f32_bf16(a.z); o[3] = (short)f32_bf16(a.w);
    o[4] = (short)f32_bf16(b.x); o[5] = (short)f32_bf16(b.y);
    o[6] = (short)f32_bf16(b.z); o[7] = (short)f32_bf16(b.w);
    *(bf16x8*)(kp + p * 8) = o;
  }
  __syncthreads();
  u16* vp = vpre + (size_t)h * 262144 + (size_t)t * 8192;
#pragma unroll
  for (int j = 0; j < 4; ++j) {
    int p = j * 256 + tid;
    int d = p >> 3;
    int cb = (p & 7) ^ (d & 7);
    bf16x8 g;
#pragma unroll
    for (int e = 0; e < 8; ++e) g[e] = (short)Vb[cb * 8 + e][d];
    *(bf16x8*)(vp + p * 8) = g;
  }
}

// ---------------- Stage 1a: est scores (f32, causal-masked, scaled) ----------------
__global__ __launch_bounds__(256) void est_kernel(const float* __restrict__ q,
                                                  const float* __restrict__ k,
                                                  float* __restrict__ scores) {
  int cc = blockIdx.x;
  int h = blockIdx.y;
  int tid = threadIdx.x;
  int ty = tid >> 4, tx = tid & 15;
  __shared__ float Qs[64][36];
  __shared__ float Ks[64][36];
  float acc[4][4];
#pragma unroll
  for (int i = 0; i < 4; ++i)
#pragma unroll
    for (int j = 0; j < 4; ++j) acc[i][j] = 0.f;
  const float* qbase = q + ((size_t)h * S_LEN + (S_LEN - LAST_Q)) * D_DIM;
  const float* kbase = k + ((size_t)h * S_LEN + cc * 64) * D_DIM;
  for (int dc = 0; dc < 4; ++dc) {
    __syncthreads();
    for (int i = tid; i < 512; i += 256) {
      int r = i >> 3, s = i & 7;
      float4 a = *(const float4*)(qbase + (size_t)r * D_DIM + dc * 32 + s * 4);
      *(float4*)&Qs[r][s * 4] = a;
      float4 b = *(const float4*)(kbase + (size_t)r * D_DIM + dc * 32 + s * 4);
      *(float4*)&Ks[r][s * 4] = b;
    }
    __syncthreads();
#pragma unroll
    for (int d4 = 0; d4 < 8; ++d4) {
      float4 qv[4], kv[4];
#pragma unroll
      for (int i = 0; i < 4; ++i) qv[i] = *(const float4*)&Qs[ty + 16 * i][d4 * 4];
#pragma unroll
      for (int j = 0; j < 4; ++j) kv[j] = *(const float4*)&Ks[tx + 16 * j][d4 * 4];
#pragma unroll
      for (int i = 0; i < 4; ++i)
#pragma unroll
        for (int j = 0; j < 4; ++j)
          acc[i][j] += qv[i].x * kv[j].x + qv[i].y * kv[j].y + qv[i].z * kv[j].z + qv[i].w * kv[j].w;
    }
  }
#pragma unroll
  for (int i = 0; i < 4; ++i) {
    int rl = ty + 16 * i;
    int rg = (S_LEN - LAST_Q) + rl;
#pragma unroll
    for (int j = 0; j < 4; ++j) {
      int cg = cc * 64 + tx + 16 * j;
      float vv = (cg <= rg) ? acc[i][j] * SCALE_F : -1e30f;
      scores[((size_t)h * LAST_Q + rl) * S_LEN + cg] = vv;
    }
  }
}

// ---------------- Stage 1b: softmax partials ----------------
__global__ __launch_bounds__(256) void soft_partial_kernel(const float* __restrict__ scores,
                                                           float* __restrict__ part) {
  int h = blockIdx.x, rg = blockIdx.y;
  int tid = threadIdx.x;
  int wave = tid >> 6, lane = tid & 63;
  __shared__ float vs[2048];
  __shared__ float ss[2048];
  __shared__ float red[4];
  int i0 = tid * 8;
#pragma unroll
  for (int e = 0; e < 8; ++e) { vs[i0 + e] = 0.f; ss[i0 + e] = 0.f; }
  for (int rr = 0; rr < 8; ++rr) {
    int r = rg * 8 + rr;
    const float* sp = scores + ((size_t)h * LAST_Q + r) * S_LEN;
    float4 a = *(const float4*)(sp + i0);
    float4 b = *(const float4*)(sp + i0 + 4);
    float x[8] = {a.x, a.y, a.z, a.w, b.x, b.y, b.z, b.w};
    float wm = -1e30f;
#pragma unroll
    for (int e = 0; e < 8; ++e) wm = fmaxf(wm, x[e]);
#pragma unroll
    for (int mk = 1; mk < 64; mk <<= 1) wm = fmaxf(wm, __shfl_xor(wm, mk, 64));
    __syncthreads();
    if (lane == 0) red[wave] = wm;
    __syncthreads();
    float m = fmaxf(fmaxf(red[0], red[1]), fmaxf(red[2], red[3]));
    float psum = 0.f;
#pragma unroll
    for (int e = 0; e < 8; ++e) { x[e] = __expf(x[e] - m); psum += x[e]; }
#pragma unroll
    for (int mk = 1; mk < 64; mk <<= 1) psum += __shfl_xor(psum, mk, 64);
    __syncthreads();
    if (lane == 0) red[wave] = psum;
    __syncthreads();
    float inv = 1.f / (red[0] + red[1] + red[2] + red[3]);
    int rgl = (S_LEN - LAST_Q) + r;
#pragma unroll
    for (int e = 0; e < 8; ++e) {
      float p = x[e] * inv;
      int i = i0 + e;
      vs[i] += p;
      int d = rgl - i;
      if (d >= 0) ss[d] += p;
    }
  }
  __syncthreads();
  float* pb = part + ((size_t)(h * 8 + rg)) * 4096;
#pragma unroll
  for (int e = 0; e < 8; ++e) { pb[i0 + e] = vs[i0 + e]; pb[2048 + i0 + e] = ss[i0 + e]; }
}

// ---------------- Stage 1c: fused reduce + top-k -> bitmasks ----------------
__global__ __launch_bounds__(256) void topk_kernel(const float* __restrict__ part,
                                                   u64* __restrict__ vbits,
                                                   u64* __restrict__ sbits) {
  int h = blockIdx.x;
  int which = blockIdx.y;
  u64* dst = which ? (sbits + h * 32) : (vbits + h * 32);
  u32 K = which ? 512u : 256u;
  int ninf = which ? 64 : 4;
  int tid = threadIdx.x;
  int lane = tid & 63, wid = tid >> 6;
  __shared__ u32 keys[2048];
  __shared__ u32 hist[256];
  __shared__ u32 wpart[4];
  __shared__ u32 sh_pref, sh_kth;
  __shared__ u64 mbw[32];
  int i0 = tid * 8;
  float accv[8] = {0.f, 0.f, 0.f, 0.f, 0.f, 0.f, 0.f, 0.f};
  for (int rg = 0; rg < 8; ++rg) {
    const float* pp = part + ((size_t)(h * 8 + rg)) * 4096 + which * 2048 + i0;
    float4 a = *(const float4*)pp;
    float4 b = *(const float4*)(pp + 4);
    accv[0] += a.x; accv[1] += a.y; accv[2] += a.z; accv[3] += a.w;
    accv[4] += b.x; accv[5] += b.y; accv[6] += b.z; accv[7] += b.w;
  }
#pragma unroll
  for (int e = 0; e < 8; ++e) {
    int i = i0 + e;
    keys[i] = (i < ninf) ? 0x7F800000u : __float_as_uint(accv[e]);
  }
  __syncthreads();
  u32 prefix = 0;
  u32 kth = K;
  for (int shift = 24; shift >= 0; shift -= 8) {
    hist[tid] = 0;
    __syncthreads();
#pragma unroll
    for (int e = 0; e < 8; ++e) {
      u32 kk = keys[i0 + e];
      if (shift == 24 || (kk >> (shift + 8)) == (prefix >> (shift + 8)))
        atomicAdd(&hist[(kk >> shift) & 255], 1u);
    }
    __syncthreads();
    u32 v = hist[tid];
    u32 x = v;
#pragma unroll
    for (int off = 1; off < 64; off <<= 1) {
      u32 o = __shfl_up(x, off, 64);
      if (lane >= off) x += o;
    }
    if (lane == 63) wpart[wid] = x;
    __syncthreads();
    u32 base = 0;
    for (int w2 = 0; w2 < wid; ++w2) base += wpart[w2];
    u32 T = wpart[0] + wpart[1] + wpart[2] + wpart[3];
    u32 Pincl = x + base;
    u32 Sb = T - Pincl + v;
    u32 Sn = T - Pincl;
    if (Sb >= kth && Sn < kth) {
      sh_pref = prefix | ((u32)tid << shift);
      sh_kth = kth - Sn;
    }
    __syncthreads();
    prefix = sh_pref;
    kth = sh_kth;
    __syncthreads();
  }
  u32 t = prefix;
  u32 cnt = 0;
#pragma unroll
  for (int e = 0; e < 8; ++e) cnt += (keys[i0 + e] == t) ? 1u : 0u;
  u32 x = cnt;
#pragma unroll
  for (int off = 1; off < 64; off <<= 1) {
    u32 o = __shfl_up(x, off, 64);
    if (lane >= off) x += o;
  }
  if (lane == 63) wpart[wid] = x;
  __syncthreads();
  u32 base = 0;
  for (int w2 = 0; w2 < wid; ++w2) base += wpart[w2];
  u32 exc = x + base - cnt;
  unsigned char myb = 0;
  u32 seen = 0;
#pragma unroll
  for (int e = 0; e < 8; ++e) {
    u32 kk = keys[i0 + e];
    bool in = (kk > t) || (kk == t && (exc + seen) < kth);
    if (kk == t) ++seen;
    myb |= (in ? 1u : 0u) << e;
  }
  ((unsigned char*)mbw)[tid] = myb;
  __syncthreads();
  if (tid < 32) dst[tid] = mbw[tid];
}

// ---------------- per-tile flash attention compute (verified R2 fragment layouts) ----------------
static __device__ __forceinline__ void tile_compute(
    const u16* __restrict__ Ksb, const u16* __restrict__ Vtb, u16* __restrict__ Psw,
    const u64* __restrict__ smp_, u64 vword,
    int c0, int q0, int grp, int ln,
    const bf16x8* qf, f32x4* of, float* mr, float* ls) {
  int qr0 = q0 + grp * 4;
  // QK^T
  f32x4 sfr[4];
#pragma unroll
  for (int nb = 0; nb < 4; ++nb) {
    f32x4 acc = (f32x4){0.f, 0.f, 0.f, 0.f};
#pragma unroll
    for (int ks = 0; ks < 4; ++ks) {
      bf16x8 kf = *(const bf16x8*)&Ksb[(nb * 16 + ln) * 128 + (((ks * 4 + grp) ^ ln) << 3)];
      acc = __builtin_amdgcn_mfma_f32_16x16x32_bf16(qf[ks], kf, acc, 0, 0, 0);
    }
    sfr[nb] = acc;
  }
  // raw row max
  f32x4 tm = sfr[0];
#pragma unroll
  for (int nb = 1; nb < 4; ++nb)
#pragma unroll
    for (int j = 0; j < 4; ++j) tm[j] = fmaxf(tm[j], sfr[nb][j]);
#pragma unroll
  for (int mk = 1; mk <= 8; mk <<= 1)
#pragma unroll
    for (int j = 0; j < 4; ++j) tm[j] = fmaxf(tm[j], __shfl_xor(tm[j], mk, 64));
  // deferred rescale (T13)
  float over = fmaxf(fmaxf(tm[0] - mr[0], tm[1] - mr[1]),
                     fmaxf(tm[2] - mr[2], tm[3] - mr[3]));
  if (__any(over > RESCALE_THR)) {
#pragma unroll
    for (int j = 0; j < 4; ++j) {
      float mn = fmaxf(mr[j], tm[j]);
      float ex = exp2f(mr[j] - mn);
      mr[j] = mn;
      ls[j] *= ex;
#pragma unroll
      for (int db = 0; db < 8; ++db) of[db][j] *= ex;
    }
  }
  // mask + p = exp2 + Ps stash
  int Cthr = qr0 - (c0 + ln);
  float rs[4] = {0.f, 0.f, 0.f, 0.f};
  bool fast = (c0 >= q0 - 48);  // diagonal region: slash-local keeps all causal
  u64 W = 0ull;
  if (!fast) {
    int b = Cthr - 48;  // >= 1 here (see fast condition alignment)
    int w0i = b >> 6;
    int sh = b & 63;
    u64 lo = smp_[w0i];
    u64 hi = smp_[w0i + 1];
    W = (sh == 0) ? lo : ((lo >> sh) | (hi << (64 - sh)));
  }
#pragma unroll
  for (int nb = 0; nb < 4; ++nb) {
    u32 km;
    if (fast) {
      int thr = 16 * nb - Cthr;  // keep j >= thr
      km = (thr <= 0) ? 0xFu : ((thr >= 4) ? 0u : ((0xFu << thr) & 0xFu));
    } else {
      u32 nib = (u32)(W >> (48 - 16 * nb)) & 0xFu;
      u32 vbit = (u32)(vword >> (nb * 16 + ln)) & 1u;
      km = vbit ? 0xFu : nib;
    }
#pragma unroll
    for (int j = 0; j < 4; ++j) {
      float p = exp2f(sfr[nb][j] - mr[j]);
      p = ((km >> j) & 1u) ? p : 0.f;
      rs[j] += p;
      Psw[(grp * 4 + j) * 72 + nb * 16 + ln] = (u16)((__float_as_uint(p) + 0x8000u) >> 16);
    }
  }
#pragma unroll
  for (int mk = 1; mk <= 8; mk <<= 1)
#pragma unroll
    for (int j = 0; j < 4; ++j) rs[j] += __shfl_xor(rs[j], mk, 64);
#pragma unroll
  for (int j = 0; j < 4; ++j) ls[j] += rs[j];
  // PV
#pragma unroll
  for (int ks2 = 0; ks2 < 2; ++ks2) {
    bf16x8 pa = *(const bf16x8*)&Psw[ln * 72 + ks2 * 32 + grp * 8];
#pragma unroll
    for (int db = 0; db < 8; ++db) {
      int d = db * 16 + ln;
      bf16x8 vf = *(const bf16x8*)&Vtb[d * 64 + ((((ks2 << 2) | grp) ^ (ln & 7)) << 3)];
      of[db] = __builtin_amdgcn_mfma_f32_16x16x32_bf16(pa, vf, of[db], 0, 0, 0);
    }
  }
}

// ---------------- Stage 2: dual-qtile balanced flash attention ----------------
// grid 512 (32 h x 16 idx), 256 threads. Block owns qtiles idx (A) and 31-idx (B):
// constant 33 tile-computes per wave -> structurally balanced across CUs.
template <bool PRE>
__global__ __launch_bounds__(256, 2) void attn_kernel(const float* __restrict__ q,
                                                      const float* __restrict__ kk,
                                                      const float* __restrict__ vv,
                                                      const u16* __restrict__ kpre,
                                                      const u16* __restrict__ vpre,
                                                      const u64* __restrict__ vbits,
                                                      const u64* __restrict__ sbits,
                                                      float* __restrict__ out) {
  int bid = blockIdx.x;
  int logical = (bid & 7) * 64 + (bid >> 3);  // 4 heads per XCD for K/V L2 locality
  int h = logical >> 4;
  int idx = logical & 15;
  int qtA = idx, qtB = 31 - idx;
  int tid = threadIdx.x;
  int wave = tid >> 6, lane = tid & 63;
  int grp = lane >> 4, ln = lane & 15;

  __shared__ u16 Ks[2][8192];   // [buf][64 rows x 128], XOR-swizzled 16B groups
  __shared__ u16 Vt[2][8192];   // [buf][128 d x 64], XOR-swizzled
  __shared__ u16 Ps[4][1152];   // per-wave P, 16 x 72
  __shared__ u64 smp[34];

  if (tid < 32) smp[tid] = sbits[h * 32 + tid];
  else if (tid < 34) smp[tid] = 0ull;

  int q0A = qtA * 64 + wave * 16;
  int q0B = qtB * 64 + wave * 16;

  // Q fragments for both qtiles (QSCALE folded)
  bf16x8 qfA[4], qfB[4];
#pragma unroll
  for (int w2 = 0; w2 < 2; ++w2) {
    int q0 = w2 ? q0B : q0A;
    const float* qrow = q + ((size_t)h * S_LEN + q0 + ln) * D_DIM;
#pragma unroll
    for (int ks = 0; ks < 4; ++ks) {
      const float* p = qrow + ks * 32 + grp * 8;
      float4 a = *(const float4*)p;
      float4 b = *(const float4*)(p + 4);
      bf16x8 f;
      f[0] = (short)f32_bf16(a.x * QSCALE); f[1] = (short)f32_bf16(a.y * QSCALE);
      f[2] = (short)f32_bf16(a.z * QSCALE); f[3] = (short)f32_bf16(a.w * QSCALE);
      f[4] = (short)f32_bf16(b.x * QSCALE); f[5] = (short)f32_bf16(b.y * QSCALE);
      f[6] = (short)f32_bf16(b.z * QSCALE); f[7] = (short)f32_bf16(b.w * QSCALE);
      if (w2) qfB[ks] = f; else qfA[ks] = f;
    }
  }
  f32x4 ofA[8], ofB[8];
#pragma unroll
  for (int i = 0; i < 8; ++i) {
    ofA[i] = (f32x4){0.f, 0.f, 0.f, 0.f};
    ofB[i] = (f32x4){0.f, 0.f, 0.f, 0.f};
  }
  float mrA[4] = {-1e30f, -1e30f, -1e30f, -1e30f};
  float mrB[4] = {-1e30f, -1e30f, -1e30f, -1e30f};
  float lsA[4] = {0.f, 0.f, 0.f, 0.f};
  float lsB[4] = {0.f, 0.f, 0.f, 0.f};

  const u16* kp = kpre + (size_t)h * 262144;
  const u16* vp = vpre + (size_t)h * 262144;
  const float* kfb = kk + (size_t)h * S_LEN * D_DIM;
  const float* vfb = vv + (size_t)h * S_LEN * D_DIM;
  const u64* vwp = vbits + h * 32;
  int nt = qtB + 1;

  // async DMA staging: linear global_load_lds from pre-swizzled layouts (T2 via m173)
  auto issue_tile = [&](int t, int b) {
    const u16* ksrc = kp + (size_t)t * 8192;
    const u16* vsrc = vp + (size_t)t * 8192;
#pragma unroll
    for (int i = 0; i < 4; ++i) {
      int chunk = wave * 4 + i;
      __builtin_amdgcn_global_load_lds(
          (const __attribute__((address_space(1))) u32*)(const void*)(ksrc + (size_t)(chunk * 64 + lane) * 8),
          (__attribute__((address_space(3))) u32*)(void*)(&Ks[b][chunk * 512]), 16, 0, 0);
      __builtin_amdgcn_global_load_lds(
          (const __attribute__((address_space(1))) u32*)(const void*)(vsrc + (size_t)(chunk * 64 + lane) * 8),
          (__attribute__((address_space(3))) u32*)(void*)(&Vt[b][chunk * 512]), 16, 0, 0);
    }
  };

  if constexpr (PRE) issue_tile(0, 0);
  __syncthreads();  // smp visible; tile 0 DMA drained (vmcnt0 at barrier)

  for (int t = 0; t < nt; ++t) {
    int cur;
    if constexpr (PRE) {
      cur = t & 1;
      if (t + 1 < nt) issue_tile(t + 1, cur ^ 1);  // lands by this iter's end barrier
    } else {
      cur = 0;
      // in-kernel f32->bf16 staging (fallback)
      int c0f = t * 64;
      for (int i = tid; i < 512; i += 256) {
        int r = i >> 3, s = i & 7;
        const float* srcp = kfb + (size_t)(c0f + r) * D_DIM + s * 16;
        float4 f0 = *(const float4*)(srcp);
        float4 f1 = *(const float4*)(srcp + 4);
        float4 f2 = *(const float4*)(srcp + 8);
        float4 f3 = *(const float4*)(srcp + 12);
        bf16x8 t0, t1;
        t0[0] = (short)f32_bf16(f0.x); t0[1] = (short)f32_bf16(f0.y);
        t0[2] = (short)f32_bf16(f0.z); t0[3] = (short)f32_bf16(f0.w);
        t0[4] = (short)f32_bf16(f1.x); t0[5] = (short)f32_bf16(f1.y);
        t0[6] = (short)f32_bf16(f1.z); t0[7] = (short)f32_bf16(f1.w);
        t1[0] = (short)f32_bf16(f2.x); t1[1] = (short)f32_bf16(f2.y);
        t1[2] = (short)f32_bf16(f2.z); t1[3] = (short)f32_bf16(f2.w);
        t1[4] = (short)f32_bf16(f3.x); t1[5] = (short)f32_bf16(f3.y);
        t1[6] = (short)f32_bf16(f3.z); t1[7] = (short)f32_bf16(f3.w);
        int cb0 = s * 2, cb1 = s * 2 + 1;
        *(bf16x8*)&Ks[0][r * 128 + ((cb0 ^ (r & 15)) << 3)] = t0;
        *(bf16x8*)&Ks[0][r * 128 + ((cb1 ^ (r & 15)) << 3)] = t1;
      }
      for (int i = tid; i < 512; i += 256) {
        int r = i >> 3, s = i & 7;
        const float* srcp = vfb + (size_t)(c0f + r) * D_DIM + s * 16;
#pragma unroll
        for (int x = 0; x < 16; x += 4) {
          float4 f4 = *(const float4*)(srcp + x);
          int d0 = s * 16 + x;
          float vals[4] = {f4.x, f4.y, f4.z, f4.w};
#pragma unroll
          for (int y = 0; y < 4; ++y) {
            int d = d0 + y;
            Vt[0][d * 64 + (((r >> 3) ^ (d & 7)) << 3) + (r & 7)] = f32_bf16(vals[y]);
          }
        }
      }
      __syncthreads();
    }

    int c0 = t * 64;
    u64 vword = vwp[t];
    tile_compute(Ks[cur], Vt[cur], Ps[wave], smp, vword, c0, q0B, grp, ln, qfB, ofB, mrB, lsB);
    if (t <= qtA)
      tile_compute(Ks[cur], Vt[cur], Ps[wave], smp, vword, c0, q0A, grp, ln, qfA, ofA, mrA, lsA);
    __syncthreads();
  }

  // epilogue: both qtiles
#pragma unroll
  for (int j = 0; j < 4; ++j) { lsA[j] = 1.f / lsA[j]; lsB[j] = 1.f / lsB[j]; }
  float* obA = out + ((size_t)h * S_LEN + q0A) * D_DIM;
  float* obB = out + ((size_t)h * S_LEN + q0B) * D_DIM;
#pragma unroll
  for (int db = 0; db < 8; ++db)
#pragma unroll
    for (int j = 0; j < 4; ++j) {
      obA[(size_t)(grp * 4 + j) * D_DIM + db * 16 + ln] = ofA[db][j] * lsA[j];
      obB[(size_t)(grp * 4 + j) * D_DIM + db * 16 + ln] = ofB[db][j] * lsB[j];
    }
}

extern "C" void kernel_launch(void* const* d_in, const int* in_sizes, int n_in,
                              void* d_out, int out_size, void* d_ws, size_t ws_size,
                              hipStream_t stream) {
  const float* q = (const float*)d_in[0];
  const float* k = (const float*)d_in[1];
  const float* v = (const float*)d_in[2];
  float* out = (float*)d_out;
  // d_out scratch (floats): scores [0,4194304), partials [4194304,5242880). Overwritten by attn.
  float* scores = out;
  float* part = out + 4194304;
  u64* vbits = (u64*)d_ws;
  u64* sbits = vbits + 1024;
  const size_t PRE_NEED = 16384 + 2ull * 16777216;
  bool pre = ws_size >= PRE_NEED;
  u16* kpre = (u16*)((char*)d_ws + 16384);
  u16* vpre = kpre + 8388608;

  if (pre) conv_kernel<<<1024, 256, 0, stream>>>(k, v, kpre, vpre);
  est_kernel<<<dim3(32, 32), 256, 0, stream>>>(q, k, scores);
  soft_partial_kernel<<<dim3(32, 8), 256, 0, stream>>>(scores, part);
  topk_kernel<<<dim3(32, 2), 256, 0, stream>>>(part, vbits, sbits);
  if (pre)
    attn_kernel<true><<<512, 256, 0, stream>>>(q, k, v, kpre, vpre, vbits, sbits, out);
  else
    attn_kernel<false><<<512, 256, 0, stream>>>(q, k, v, kpre, vpre, vbits, sbits, out);
}

// Round 6
// 161.657 us; speedup vs baseline: 1.5280x; 1.5280x over previous
//
#include <hip/hip_runtime.h>
#include <hip/hip_bf16.h>

#define S_LEN 2048
#define NH 32
#define D_DIM 128
#define LAST_Q 64
#define SCALE_F 0.08838834764831845f
#define QSCALE (0.08838834764831845f * 1.4426950408889634f)  // scale * log2(e)
#define RESCALE_THR 11.54f

typedef __attribute__((ext_vector_type(8))) short bf16x8;
typedef __attribute__((ext_vector_type(4))) float f32x4;
typedef unsigned long long u64;
typedef unsigned int u32;
typedef unsigned short u16;

static __device__ __forceinline__ u16 f32_bf16(float f) {
  u32 u = __float_as_uint(f);
  u32 r = (u + 0x7FFFu + ((u >> 16) & 1u)) >> 16;
  return (u16)r;
}

static __device__ __forceinline__ u32 cvt_pk_bf16(float lo, float hi) {
  u32 r;
  asm("v_cvt_pk_bf16_f32 %0, %1, %2" : "=v"(r) : "v"(lo), "v"(hi));
  return r;
}

// ---------------- Stage 0: preconvert to PRE-SWIZZLED bf16 layouts ----------------
// kpre[h][t][p]: r=p>>4, g=(p&15)^(r&15): holds K[h][t*64+r][g*8..+8).
// vpre[h][t][p]: d=p>>3, cb=(p&7)^(d&7): holds V[h][t*64+cb*8+e][d], e<8.
__global__ __launch_bounds__(256) void conv_kernel(const float* __restrict__ k,
                                                   const float* __restrict__ v,
                                                   u16* __restrict__ kpre,
                                                   u16* __restrict__ vpre) {
  int bid = blockIdx.x;
  int t = bid & 31, h = bid >> 5;
  int tid = threadIdx.x;
  int c0 = t * 64;
  __shared__ u16 Vb[64][136];
  for (int i = tid; i < 512; i += 256) {
    int r = i >> 3, s = i & 7;
    const float* srcp = v + ((size_t)(h * S_LEN + c0 + r)) * D_DIM + s * 16;
    float4 f0 = *(const float4*)(srcp);
    float4 f1 = *(const float4*)(srcp + 4);
    float4 f2 = *(const float4*)(srcp + 8);
    float4 f3 = *(const float4*)(srcp + 12);
    bf16x8 t0, t1;
    t0[0] = (short)f32_bf16(f0.x); t0[1] = (short)f32_bf16(f0.y);
    t0[2] = (short)f32_bf16(f0.z); t0[3] = (short)f32_bf16(f0.w);
    t0[4] = (short)f32_bf16(f1.x); t0[5] = (short)f32_bf16(f1.y);
    t0[6] = (short)f32_bf16(f1.z); t0[7] = (short)f32_bf16(f1.w);
    t1[0] = (short)f32_bf16(f2.x); t1[1] = (short)f32_bf16(f2.y);
    t1[2] = (short)f32_bf16(f2.z); t1[3] = (short)f32_bf16(f2.w);
    t1[4] = (short)f32_bf16(f3.x); t1[5] = (short)f32_bf16(f3.y);
    t1[6] = (short)f32_bf16(f3.z); t1[7] = (short)f32_bf16(f3.w);
    *(bf16x8*)&Vb[r][s * 16] = t0;
    *(bf16x8*)&Vb[r][s * 16 + 8] = t1;
  }
  u16* kp = kpre + (size_t)h * 262144 + (size_t)t * 8192;
#pragma unroll
  for (int j = 0; j < 4; ++j) {
    int p = j * 256 + tid;
    int r = p >> 4;
    int g = (p & 15) ^ (r & 15);
    const float* srcp = k + ((size_t)(h * S_LEN + c0 + r)) * D_DIM + g * 8;
    float4 a = *(const float4*)srcp;
    float4 b = *(const float4*)(srcp + 4);
    bf16x8 o;
    o[0] = (short)f32_bf16(a.x); o[1] = (short)f32_bf16(a.y);
    o[2] = (short)f32_bf16(a.z); o[3] = (short)f32_bf16(a.w);
    o[4] = (short)f32_bf16(b.x); o[5] = (short)f32_bf16(b.y);
    o[6] = (short)f32_bf16(b.z); o[7] = (short)f32_bf16(b.w);
    *(bf16x8*)(kp + p * 8) = o;
  }
  __syncthreads();
  u16* vp = vpre + (size_t)h * 262144 + (size_t)t * 8192;
#pragma unroll
  for (int j = 0; j < 4; ++j) {
    int p = j * 256 + tid;
    int d = p >> 3;
    int cb = (p & 7) ^ (d & 7);
    bf16x8 g;
#pragma unroll
    for (int e = 0; e < 8; ++e) g[e] = (short)Vb[cb * 8 + e][d];
    *(bf16x8*)(vp + p * 8) = g;
  }
}

// ---------------- Stage 1a: est scores ----------------
__global__ __launch_bounds__(256) void est_kernel(const float* __restrict__ q,
                                                  const float* __restrict__ k,
                                                  float* __restrict__ scores) {
  int cc = blockIdx.x;
  int h = blockIdx.y;
  int tid = threadIdx.x;
  int ty = tid >> 4, tx = tid & 15;
  __shared__ float Qs[64][36];
  __shared__ float Ks[64][36];
  float acc[4][4];
#pragma unroll
  for (int i = 0; i < 4; ++i)
#pragma unroll
    for (int j = 0; j < 4; ++j) acc[i][j] = 0.f;
  const float* qbase = q + ((size_t)h * S_LEN + (S_LEN - LAST_Q)) * D_DIM;
  const float* kbase = k + ((size_t)h * S_LEN + cc * 64) * D_DIM;
  for (int dc = 0; dc < 4; ++dc) {
    __syncthreads();
    for (int i = tid; i < 512; i += 256) {
      int r = i >> 3, s = i & 7;
      float4 a = *(const float4*)(qbase + (size_t)r * D_DIM + dc * 32 + s * 4);
      *(float4*)&Qs[r][s * 4] = a;
      float4 b = *(const float4*)(kbase + (size_t)r * D_DIM + dc * 32 + s * 4);
      *(float4*)&Ks[r][s * 4] = b;
    }
    __syncthreads();
#pragma unroll
    for (int d4 = 0; d4 < 8; ++d4) {
      float4 qv[4], kv[4];
#pragma unroll
      for (int i = 0; i < 4; ++i) qv[i] = *(const float4*)&Qs[ty + 16 * i][d4 * 4];
#pragma unroll
      for (int j = 0; j < 4; ++j) kv[j] = *(const float4*)&Ks[tx + 16 * j][d4 * 4];
#pragma unroll
      for (int i = 0; i < 4; ++i)
#pragma unroll
        for (int j = 0; j < 4; ++j)
          acc[i][j] += qv[i].x * kv[j].x + qv[i].y * kv[j].y + qv[i].z * kv[j].z + qv[i].w * kv[j].w;
    }
  }
#pragma unroll
  for (int i = 0; i < 4; ++i) {
    int rl = ty + 16 * i;
    int rg = (S_LEN - LAST_Q) + rl;
#pragma unroll
    for (int j = 0; j < 4; ++j) {
      int cg = cc * 64 + tx + 16 * j;
      float vv = (cg <= rg) ? acc[i][j] * SCALE_F : -1e30f;
      scores[((size_t)h * LAST_Q + rl) * S_LEN + cg] = vv;
    }
  }
}

// ---------------- Stage 1b: softmax partials ----------------
__global__ __launch_bounds__(256) void soft_partial_kernel(const float* __restrict__ scores,
                                                           float* __restrict__ part) {
  int h = blockIdx.x, rg = blockIdx.y;
  int tid = threadIdx.x;
  int wave = tid >> 6, lane = tid & 63;
  __shared__ float vs[2048];
  __shared__ float ss[2048];
  __shared__ float red[4];
  int i0 = tid * 8;
#pragma unroll
  for (int e = 0; e < 8; ++e) { vs[i0 + e] = 0.f; ss[i0 + e] = 0.f; }
  for (int rr = 0; rr < 8; ++rr) {
    int r = rg * 8 + rr;
    const float* sp = scores + ((size_t)h * LAST_Q + r) * S_LEN;
    float4 a = *(const float4*)(sp + i0);
    float4 b = *(const float4*)(sp + i0 + 4);
    float x[8] = {a.x, a.y, a.z, a.w, b.x, b.y, b.z, b.w};
    float wm = -1e30f;
#pragma unroll
    for (int e = 0; e < 8; ++e) wm = fmaxf(wm, x[e]);
#pragma unroll
    for (int mk = 1; mk < 64; mk <<= 1) wm = fmaxf(wm, __shfl_xor(wm, mk, 64));
    __syncthreads();
    if (lane == 0) red[wave] = wm;
    __syncthreads();
    float m = fmaxf(fmaxf(red[0], red[1]), fmaxf(red[2], red[3]));
    float psum = 0.f;
#pragma unroll
    for (int e = 0; e < 8; ++e) { x[e] = __expf(x[e] - m); psum += x[e]; }
#pragma unroll
    for (int mk = 1; mk < 64; mk <<= 1) psum += __shfl_xor(psum, mk, 64);
    __syncthreads();
    if (lane == 0) red[wave] = psum;
    __syncthreads();
    float inv = 1.f / (red[0] + red[1] + red[2] + red[3]);
    int rgl = (S_LEN - LAST_Q) + r;
#pragma unroll
    for (int e = 0; e < 8; ++e) {
      float p = x[e] * inv;
      int i = i0 + e;
      vs[i] += p;
      int d = rgl - i;
      if (d >= 0) ss[d] += p;
    }
  }
  __syncthreads();
  float* pb = part + ((size_t)(h * 8 + rg)) * 4096;
#pragma unroll
  for (int e = 0; e < 8; ++e) { pb[i0 + e] = vs[i0 + e]; pb[2048 + i0 + e] = ss[i0 + e]; }
}

// ---------------- Stage 1c: fused reduce + top-k -> bitmasks ----------------
__global__ __launch_bounds__(256) void topk_kernel(const float* __restrict__ part,
                                                   u64* __restrict__ vbits,
                                                   u64* __restrict__ sbits) {
  int h = blockIdx.x;
  int which = blockIdx.y;
  u64* dst = which ? (sbits + h * 32) : (vbits + h * 32);
  u32 K = which ? 512u : 256u;
  int ninf = which ? 64 : 4;
  int tid = threadIdx.x;
  int lane = tid & 63, wid = tid >> 6;
  __shared__ u32 keys[2048];
  __shared__ u32 hist[256];
  __shared__ u32 wpart[4];
  __shared__ u32 sh_pref, sh_kth;
  __shared__ u64 mbw[32];
  int i0 = tid * 8;
  float accv[8] = {0.f, 0.f, 0.f, 0.f, 0.f, 0.f, 0.f, 0.f};
  for (int rg = 0; rg < 8; ++rg) {
    const float* pp = part + ((size_t)(h * 8 + rg)) * 4096 + which * 2048 + i0;
    float4 a = *(const float4*)pp;
    float4 b = *(const float4*)(pp + 4);
    accv[0] += a.x; accv[1] += a.y; accv[2] += a.z; accv[3] += a.w;
    accv[4] += b.x; accv[5] += b.y; accv[6] += b.z; accv[7] += b.w;
  }
#pragma unroll
  for (int e = 0; e < 8; ++e) {
    int i = i0 + e;
    keys[i] = (i < ninf) ? 0x7F800000u : __float_as_uint(accv[e]);
  }
  __syncthreads();
  u32 prefix = 0;
  u32 kth = K;
  for (int shift = 24; shift >= 0; shift -= 8) {
    hist[tid] = 0;
    __syncthreads();
#pragma unroll
    for (int e = 0; e < 8; ++e) {
      u32 kk = keys[i0 + e];
      if (shift == 24 || (kk >> (shift + 8)) == (prefix >> (shift + 8)))
        atomicAdd(&hist[(kk >> shift) & 255], 1u);
    }
    __syncthreads();
    u32 v = hist[tid];
    u32 x = v;
#pragma unroll
    for (int off = 1; off < 64; off <<= 1) {
      u32 o = __shfl_up(x, off, 64);
      if (lane >= off) x += o;
    }
    if (lane == 63) wpart[wid] = x;
    __syncthreads();
    u32 base = 0;
    for (int w2 = 0; w2 < wid; ++w2) base += wpart[w2];
    u32 T = wpart[0] + wpart[1] + wpart[2] + wpart[3];
    u32 Pincl = x + base;
    u32 Sb = T - Pincl + v;
    u32 Sn = T - Pincl;
    if (Sb >= kth && Sn < kth) {
      sh_pref = prefix | ((u32)tid << shift);
      sh_kth = kth - Sn;
    }
    __syncthreads();
    prefix = sh_pref;
    kth = sh_kth;
    __syncthreads();
  }
  u32 t = prefix;
  u32 cnt = 0;
#pragma unroll
  for (int e = 0; e < 8; ++e) cnt += (keys[i0 + e] == t) ? 1u : 0u;
  u32 x = cnt;
#pragma unroll
  for (int off = 1; off < 64; off <<= 1) {
    u32 o = __shfl_up(x, off, 64);
    if (lane >= off) x += o;
  }
  if (lane == 63) wpart[wid] = x;
  __syncthreads();
  u32 base = 0;
  for (int w2 = 0; w2 < wid; ++w2) base += wpart[w2];
  u32 exc = x + base - cnt;
  unsigned char myb = 0;
  u32 seen = 0;
#pragma unroll
  for (int e = 0; e < 8; ++e) {
    u32 kk = keys[i0 + e];
    bool in = (kk > t) || (kk == t && (exc + seen) < kth);
    if (kk == t) ++seen;
    myb |= (in ? 1u : 0u) << e;
  }
  ((unsigned char*)mbw)[tid] = myb;
  __syncthreads();
  if (tid < 32) dst[tid] = mbw[tid];
}

// ---------------- Stage 2: swapped-QK flash attention, balanced static map ----------------
// grid 1024, 256 threads (4 waves x 16 q-rows). Swapped QK^T: lane owns q-row (q=ln),
// softmax in-register, P->PV via cvt_pk + shfl. LDS = K(16K) + V(16K) single-buffered
// with global_load_lds DMA; 4 blocks/CU.
template <bool PRE>
__global__ __launch_bounds__(256, 4) void attn_kernel(const float* __restrict__ q,
                                                      const float* __restrict__ kk,
                                                      const float* __restrict__ vv,
                                                      const u16* __restrict__ kpre,
                                                      const u16* __restrict__ vpre,
                                                      const u64* __restrict__ vbits,
                                                      const u64* __restrict__ sbits,
                                                      float* __restrict__ out) {
  int bid = blockIdx.x;
  // balanced static map: CU's 4 co-resident slots (same u) sum to 66 tile-units
  int u = bid & 255, s = bid >> 8;
  int h = ((u >> 5) << 2) + s;
  int v_ = u & 31;
  int qt;
  switch (s) {
    case 0: qt = v_; break;
    case 1: qt = 31 - v_; break;
    case 2: qt = (v_ + 16) & 31; break;
    default: qt = (15 - v_) & 31; break;
  }
  int tid = threadIdx.x;
  int wave = tid >> 6, lane = tid & 63;
  int grp = lane >> 4, ln = lane & 15;

  __shared__ u16 Ks[8192];
  __shared__ u16 Vt[8192];
  __shared__ u64 smp[34];

  if (tid < 34) smp[tid] = (tid == 0 || tid == 33) ? 0ull : sbits[h * 32 + tid - 1];

  int q0w = qt * 64 + wave * 16;
  // Q fragments (B-operand layout == old A-layout indexing), QSCALE folded
  bf16x8 qf[4];
  const float* qrow = q + ((size_t)h * S_LEN + q0w + ln) * D_DIM;
#pragma unroll
  for (int ks = 0; ks < 4; ++ks) {
    const float* p = qrow + ks * 32 + grp * 8;
    float4 a = *(const float4*)p;
    float4 b = *(const float4*)(p + 4);
    bf16x8 f;
    f[0] = (short)f32_bf16(a.x * QSCALE); f[1] = (short)f32_bf16(a.y * QSCALE);
    f[2] = (short)f32_bf16(a.z * QSCALE); f[3] = (short)f32_bf16(a.w * QSCALE);
    f[4] = (short)f32_bf16(b.x * QSCALE); f[5] = (short)f32_bf16(b.y * QSCALE);
    f[6] = (short)f32_bf16(b.z * QSCALE); f[7] = (short)f32_bf16(b.w * QSCALE);
    qf[ks] = f;
  }
  f32x4 of[8];
#pragma unroll
  for (int i = 0; i < 8; ++i) of[i] = (f32x4){0.f, 0.f, 0.f, 0.f};
  float mr = -1e30f;  // per-lane row state (q = q0w + ln), replicated across grp
  float ls = 0.f;

  const u16* kp = kpre + (size_t)h * 262144;
  const u16* vp = vpre + (size_t)h * 262144;
  const float* kfb = kk + (size_t)h * S_LEN * D_DIM;
  const float* vfb = vv + (size_t)h * S_LEN * D_DIM;
  const u64* vwp = vbits + h * 32;
  int nt = qt + 1;
  int sb_lane = (lane & 48) + ((lane & 48) >> 2);  // lane of q-row grp*4 (+j)

  auto issue_tile = [&](int t) {
    const u16* ksrc = kp + (size_t)t * 8192;
    const u16* vsrc = vp + (size_t)t * 8192;
#pragma unroll
    for (int i = 0; i < 4; ++i) {
      int chunk = wave * 4 + i;
      __builtin_amdgcn_global_load_lds(
          (const __attribute__((address_space(1))) u32*)(const void*)(ksrc + (size_t)(chunk * 64 + lane) * 8),
          (__attribute__((address_space(3))) u32*)(void*)(&Ks[chunk * 512]), 16, 0, 0);
      __builtin_amdgcn_global_load_lds(
          (const __attribute__((address_space(1))) u32*)(const void*)(vsrc + (size_t)(chunk * 64 + lane) * 8),
          (__attribute__((address_space(3))) u32*)(void*)(&Vt[chunk * 512]), 16, 0, 0);
    }
  };

  if constexpr (PRE) {
    issue_tile(0);
    asm volatile("s_waitcnt vmcnt(0)" ::: "memory");
  }
  __syncthreads();  // smp + tile 0 ready

  for (int t = 0; t < nt; ++t) {
    int c0 = t * 64;
    if constexpr (!PRE) {
      // fallback: VALU staging
      for (int i = tid; i < 512; i += 256) {
        int r = i >> 3, s2 = i & 7;
        const float* srcp = kfb + (size_t)(c0 + r) * D_DIM + s2 * 16;
        float4 f0 = *(const float4*)(srcp);
        float4 f1 = *(const float4*)(srcp + 4);
        float4 f2 = *(const float4*)(srcp + 8);
        float4 f3 = *(const float4*)(srcp + 12);
        bf16x8 t0, t1;
        t0[0] = (short)f32_bf16(f0.x); t0[1] = (short)f32_bf16(f0.y);
        t0[2] = (short)f32_bf16(f0.z); t0[3] = (short)f32_bf16(f0.w);
        t0[4] = (short)f32_bf16(f1.x); t0[5] = (short)f32_bf16(f1.y);
        t0[6] = (short)f32_bf16(f1.z); t0[7] = (short)f32_bf16(f1.w);
        t1[0] = (short)f32_bf16(f2.x); t1[1] = (short)f32_bf16(f2.y);
        t1[2] = (short)f32_bf16(f2.z); t1[3] = (short)f32_bf16(f2.w);
        t1[4] = (short)f32_bf16(f3.x); t1[5] = (short)f32_bf16(f3.y);
        t1[6] = (short)f32_bf16(f3.z); t1[7] = (short)f32_bf16(f3.w);
        int cb0 = s2 * 2, cb1 = s2 * 2 + 1;
        *(bf16x8*)&Ks[r * 128 + ((cb0 ^ (r & 15)) << 3)] = t0;
        *(bf16x8*)&Ks[r * 128 + ((cb1 ^ (r & 15)) << 3)] = t1;
      }
      for (int i = tid; i < 512; i += 256) {
        int r = i >> 3, s2 = i & 7;
        const float* srcp = vfb + (size_t)(c0 + r) * D_DIM + s2 * 16;
#pragma unroll
        for (int x = 0; x < 16; x += 4) {
          float4 f4 = *(const float4*)(srcp + x);
          int d0 = s2 * 16 + x;
          float vals[4] = {f4.x, f4.y, f4.z, f4.w};
#pragma unroll
          for (int y = 0; y < 4; ++y) {
            int d = d0 + y;
            Vt[d * 64 + (((r >> 3) ^ (d & 7)) << 3) + (r & 7)] = f32_bf16(vals[y]);
          }
        }
      }
      __syncthreads();
    }

    // ---- swapped QK^T: sfr[nb][jj] = S[c0+16nb+4grp+jj][q0w+ln] ----
    f32x4 sfr[4];
#pragma unroll
    for (int nb = 0; nb < 4; ++nb) {
      f32x4 acc = (f32x4){0.f, 0.f, 0.f, 0.f};
#pragma unroll
      for (int ks = 0; ks < 4; ++ks) {
        bf16x8 kf = *(const bf16x8*)&Ks[(nb * 16 + ln) * 128 + (((ks * 4 + grp) ^ ln) << 3)];
        acc = __builtin_amdgcn_mfma_f32_16x16x32_bf16(kf, qf[ks], acc, 0, 0, 0);
      }
      sfr[nb] = acc;
    }

    // ---- row max (q = ln): in-register + 2 shuffles ----
    float tm = sfr[0][0];
#pragma unroll
    for (int nb = 0; nb < 4; ++nb)
#pragma unroll
      for (int jj = 0; jj < 4; ++jj) tm = fmaxf(tm, sfr[nb][jj]);
    tm = fmaxf(tm, __shfl_xor(tm, 16, 64));
    tm = fmaxf(tm, __shfl_xor(tm, 32, 64));

    // ---- deferred rescale (T13) ----
    if (__any(tm - mr > RESCALE_THR)) {
      float mn = fmaxf(mr, tm);
      float ex = exp2f(mr - mn);
      mr = mn;
      ls *= ex;
      float e0 = __shfl(ex, sb_lane, 64);
      float e1 = __shfl(ex, sb_lane + 1, 64);
      float e2 = __shfl(ex, sb_lane + 2, 64);
      float e3 = __shfl(ex, sb_lane + 3, 64);
#pragma unroll
      for (int db = 0; db < 8; ++db) {
        of[db][0] *= e0; of[db][1] *= e1; of[db][2] *= e2; of[db][3] *= e3;
      }
    }

    // ---- mask + p = exp2 + pack ----
    int Cb = (q0w + ln) - c0 - (grp << 2);
    float rs = 0.f;
    u32 pkw[8];
    if (c0 >= q0w - 48) {
      // diagonal region: causal-only (slash d<64 always kept)
#pragma unroll
      for (int nb = 0; nb < 4; ++nb) {
        float pv[4];
#pragma unroll
        for (int jj = 0; jj < 4; ++jj) {
          bool keep = (16 * nb + jj) <= Cb;
          float p = keep ? exp2f(sfr[nb][jj] - mr) : 0.f;
          rs += p;
          pv[jj] = p;
        }
        pkw[nb * 2] = cvt_pk_bf16(pv[0], pv[1]);
        pkw[nb * 2 + 1] = cvt_pk_bf16(pv[2], pv[3]);
      }
    } else {
      int b0 = Cb - 63;
      int w0i = (b0 >> 6) + 1;
      int sh = b0 & 63;
      u64 lo = smp[w0i];
      u64 hi = smp[w0i + 1];
      u64 W = (sh == 0) ? lo : ((lo >> sh) | (hi << (64 - sh)));
      u64 vword = vwp[t];
#pragma unroll
      for (int nb = 0; nb < 4; ++nb) {
        u32 vn = (u32)(vword >> (16 * nb + 4 * grp)) & 0xFu;
        u32 sn = (u32)(W >> (60 - 16 * nb)) & 0xFu;  // bit (3-jj) = slash d for jj
        float pv[4];
#pragma unroll
        for (int jj = 0; jj < 4; ++jj) {
          u32 keep = ((vn >> jj) | (sn >> (3 - jj))) & 1u;
          float p = keep ? exp2f(sfr[nb][jj] - mr) : 0.f;
          rs += p;
          pv[jj] = p;
        }
        pkw[nb * 2] = cvt_pk_bf16(pv[0], pv[1]);
        pkw[nb * 2 + 1] = cvt_pk_bf16(pv[2], pv[3]);
      }
    }
    rs += __shfl_xor(rs, 16, 64);
    rs += __shfl_xor(rs, 32, 64);
    ls += rs;

    // ---- PV: pa via shfl of packed P ----
#pragma unroll
    for (int ks2 = 0; ks2 < 2; ++ks2) {
      int sl0 = ln + ((lane & 16) << 1);  // ln + (grp&1)*32
      int sl1 = sl0 + 16;
      u32 a0 = __shfl(pkw[ks2 * 4 + 0], sl0, 64);
      u32 a1 = __shfl(pkw[ks2 * 4 + 1], sl0, 64);
      u32 a2 = __shfl(pkw[ks2 * 4 + 0], sl1, 64);
      u32 a3 = __shfl(pkw[ks2 * 4 + 1], sl1, 64);
      u32 b0_ = __shfl(pkw[ks2 * 4 + 2], sl0, 64);
      u32 b1_ = __shfl(pkw[ks2 * 4 + 3], sl0, 64);
      u32 b2_ = __shfl(pkw[ks2 * 4 + 2], sl1, 64);
      u32 b3_ = __shfl(pkw[ks2 * 4 + 3], sl1, 64);
      bool hi2 = grp >= 2;
      union { u32 w[4]; bf16x8 v; } pu;
      pu.w[0] = hi2 ? b0_ : a0;
      pu.w[1] = hi2 ? b1_ : a1;
      pu.w[2] = hi2 ? b2_ : a2;
      pu.w[3] = hi2 ? b3_ : a3;
#pragma unroll
      for (int db = 0; db < 8; ++db) {
        int d = db * 16 + ln;
        bf16x8 vf = *(const bf16x8*)&Vt[d * 64 + ((((ks2 << 2) | grp) ^ (ln & 7)) << 3)];
        of[db] = __builtin_amdgcn_mfma_f32_16x16x32_bf16(pu.v, vf, of[db], 0, 0, 0);
      }
    }

    // ---- stage next tile ----
    if (t + 1 < nt) {
      if constexpr (PRE) {
        __builtin_amdgcn_s_barrier();   // all waves done reading Ks/Vt
        issue_tile(t + 1);
        asm volatile("s_waitcnt vmcnt(0)" ::: "memory");
        __builtin_amdgcn_s_barrier();   // staged data visible to all
      } else {
        __syncthreads();
      }
    }
  }

  // ---- epilogue: broadcast 1/ls to of-rows ----
  float invl = 1.f / ls;
  float i0 = __shfl(invl, sb_lane, 64);
  float i1 = __shfl(invl, sb_lane + 1, 64);
  float i2 = __shfl(invl, sb_lane + 2, 64);
  float i3 = __shfl(invl, sb_lane + 3, 64);
  float* ob = out + ((size_t)h * S_LEN + q0w) * D_DIM;
#pragma unroll
  for (int db = 0; db < 8; ++db) {
    ob[(size_t)(grp * 4 + 0) * D_DIM + db * 16 + ln] = of[db][0] * i0;
    ob[(size_t)(grp * 4 + 1) * D_DIM + db * 16 + ln] = of[db][1] * i1;
    ob[(size_t)(grp * 4 + 2) * D_DIM + db * 16 + ln] = of[db][2] * i2;
    ob[(size_t)(grp * 4 + 3) * D_DIM + db * 16 + ln] = of[db][3] * i3;
  }
}

extern "C" void kernel_launch(void* const* d_in, const int* in_sizes, int n_in,
                              void* d_out, int out_size, void* d_ws, size_t ws_size,
                              hipStream_t stream) {
  const float* q = (const float*)d_in[0];
  const float* k = (const float*)d_in[1];
  const float* v = (const float*)d_in[2];
  float* out = (float*)d_out;
  float* scores = out;
  float* part = out + 4194304;
  u64* vbits = (u64*)d_ws;
  u64* sbits = vbits + 1024;
  const size_t PRE_NEED = 16384 + 2ull * 16777216;
  bool pre = ws_size >= PRE_NEED;
  u16* kpre = (u16*)((char*)d_ws + 16384);
  u16* vpre = kpre + 8388608;

  if (pre) conv_kernel<<<1024, 256, 0, stream>>>(k, v, kpre, vpre);
  est_kernel<<<dim3(32, 32), 256, 0, stream>>>(q, k, scores);
  soft_partial_kernel<<<dim3(32, 8), 256, 0, stream>>>(scores, part);
  topk_kernel<<<dim3(32, 2), 256, 0, stream>>>(part, vbits, sbits);
  if (pre)
    attn_kernel<true><<<1024, 256, 0, stream>>>(q, k, v, kpre, vpre, vbits, sbits, out);
  else
    attn_kernel<false><<<1024, 256, 0, stream>>>(q, k, v, kpre, vpre, vbits, sbits, out);
}

// Round 7
// 140.875 us; speedup vs baseline: 1.7535x; 1.1475x over previous
//
#include <hip/hip_runtime.h>
#include <hip/hip_bf16.h>

#define S_LEN 2048
#define NH 32
#define D_DIM 128
#define LAST_Q 64
#define SCALE_F 0.08838834764831845f
#define QSCALE (0.08838834764831845f * 1.4426950408889634f)  // scale * log2(e)
#define RESCALE_THR 11.54f

typedef __attribute__((ext_vector_type(8))) short bf16x8;
typedef __attribute__((ext_vector_type(4))) float f32x4;
typedef unsigned long long u64;
typedef unsigned int u32;
typedef unsigned short u16;

static __device__ __forceinline__ u16 f32_bf16(float f) {
  u32 u = __float_as_uint(f);
  u32 r = (u + 0x7FFFu + ((u >> 16) & 1u)) >> 16;
  return (u16)r;
}

static __device__ __forceinline__ u32 cvt_pk_bf16(float lo, float hi) {
  u32 r;
  asm("v_cvt_pk_bf16_f32 %0, %1, %2" : "=v"(r) : "v"(lo), "v"(hi));
  return r;
}

// ---------------- Stage 0: preconvert to PRE-SWIZZLED bf16 layouts ----------------
// kpre[h][t][p]: r=p>>4, g=(p&15)^(r&15): holds K[h][t*64+r][g*8..+8).
// vpre[h][t][p]: d=p>>3, cb=(p&7)^(d&7): holds V[h][t*64+cb*8+e][d], e<8.
__global__ __launch_bounds__(256) void conv_kernel(const float* __restrict__ k,
                                                   const float* __restrict__ v,
                                                   u16* __restrict__ kpre,
                                                   u16* __restrict__ vpre) {
  int bid = blockIdx.x;
  int t = bid & 31, h = bid >> 5;
  int tid = threadIdx.x;
  int c0 = t * 64;
  __shared__ u16 Vb[64][136];
  for (int i = tid; i < 512; i += 256) {
    int r = i >> 3, s = i & 7;
    const float* srcp = v + ((size_t)(h * S_LEN + c0 + r)) * D_DIM + s * 16;
    float4 f0 = *(const float4*)(srcp);
    float4 f1 = *(const float4*)(srcp + 4);
    float4 f2 = *(const float4*)(srcp + 8);
    float4 f3 = *(const float4*)(srcp + 12);
    bf16x8 t0, t1;
    t0[0] = (short)f32_bf16(f0.x); t0[1] = (short)f32_bf16(f0.y);
    t0[2] = (short)f32_bf16(f0.z); t0[3] = (short)f32_bf16(f0.w);
    t0[4] = (short)f32_bf16(f1.x); t0[5] = (short)f32_bf16(f1.y);
    t0[6] = (short)f32_bf16(f1.z); t0[7] = (short)f32_bf16(f1.w);
    t1[0] = (short)f32_bf16(f2.x); t1[1] = (short)f32_bf16(f2.y);
    t1[2] = (short)f32_bf16(f2.z); t1[3] = (short)f32_bf16(f2.w);
    t1[4] = (short)f32_bf16(f3.x); t1[5] = (short)f32_bf16(f3.y);
    t1[6] = (short)f32_bf16(f3.z); t1[7] = (short)f32_bf16(f3.w);
    *(bf16x8*)&Vb[r][s * 16] = t0;
    *(bf16x8*)&Vb[r][s * 16 + 8] = t1;
  }
  u16* kp = kpre + (size_t)h * 262144 + (size_t)t * 8192;
#pragma unroll
  for (int j = 0; j < 4; ++j) {
    int p = j * 256 + tid;
    int r = p >> 4;
    int g = (p & 15) ^ (r & 15);
    const float* srcp = k + ((size_t)(h * S_LEN + c0 + r)) * D_DIM + g * 8;
    float4 a = *(const float4*)srcp;
    float4 b = *(const float4*)(srcp + 4);
    bf16x8 o;
    o[0] = (short)f32_bf16(a.x); o[1] = (short)f32_bf16(a.y);
    o[2] = (short)f32_bf16(a.z); o[3] = (short)f32_bf16(a.w);
    o[4] = (short)f32_bf16(b.x); o[5] = (short)f32_bf16(b.y);
    o[6] = (short)f32_bf16(b.z); o[7] = (short)f32_bf16(b.w);
    *(bf16x8*)(kp + p * 8) = o;
  }
  __syncthreads();
  u16* vp = vpre + (size_t)h * 262144 + (size_t)t * 8192;
#pragma unroll
  for (int j = 0; j < 4; ++j) {
    int p = j * 256 + tid;
    int d = p >> 3;
    int cb = (p & 7) ^ (d & 7);
    bf16x8 g;
#pragma unroll
    for (int e = 0; e < 8; ++e) g[e] = (short)Vb[cb * 8 + e][d];
    *(bf16x8*)(vp + p * 8) = g;
  }
}

// ---------------- Stage 1a: est scores ----------------
__global__ __launch_bounds__(256) void est_kernel(const float* __restrict__ q,
                                                  const float* __restrict__ k,
                                                  float* __restrict__ scores) {
  int cc = blockIdx.x;
  int h = blockIdx.y;
  int tid = threadIdx.x;
  int ty = tid >> 4, tx = tid & 15;
  __shared__ float Qs[64][36];
  __shared__ float Ks[64][36];
  float acc[4][4];
#pragma unroll
  for (int i = 0; i < 4; ++i)
#pragma unroll
    for (int j = 0; j < 4; ++j) acc[i][j] = 0.f;
  const float* qbase = q + ((size_t)h * S_LEN + (S_LEN - LAST_Q)) * D_DIM;
  const float* kbase = k + ((size_t)h * S_LEN + cc * 64) * D_DIM;
  for (int dc = 0; dc < 4; ++dc) {
    __syncthreads();
    for (int i = tid; i < 512; i += 256) {
      int r = i >> 3, s = i & 7;
      float4 a = *(const float4*)(qbase + (size_t)r * D_DIM + dc * 32 + s * 4);
      *(float4*)&Qs[r][s * 4] = a;
      float4 b = *(const float4*)(kbase + (size_t)r * D_DIM + dc * 32 + s * 4);
      *(float4*)&Ks[r][s * 4] = b;
    }
    __syncthreads();
#pragma unroll
    for (int d4 = 0; d4 < 8; ++d4) {
      float4 qv[4], kv[4];
#pragma unroll
      for (int i = 0; i < 4; ++i) qv[i] = *(const float4*)&Qs[ty + 16 * i][d4 * 4];
#pragma unroll
      for (int j = 0; j < 4; ++j) kv[j] = *(const float4*)&Ks[tx + 16 * j][d4 * 4];
#pragma unroll
      for (int i = 0; i < 4; ++i)
#pragma unroll
        for (int j = 0; j < 4; ++j)
          acc[i][j] += qv[i].x * kv[j].x + qv[i].y * kv[j].y + qv[i].z * kv[j].z + qv[i].w * kv[j].w;
    }
  }
#pragma unroll
  for (int i = 0; i < 4; ++i) {
    int rl = ty + 16 * i;
    int rg = (S_LEN - LAST_Q) + rl;
#pragma unroll
    for (int j = 0; j < 4; ++j) {
      int cg = cc * 64 + tx + 16 * j;
      float vv = (cg <= rg) ? acc[i][j] * SCALE_F : -1e30f;
      scores[((size_t)h * LAST_Q + rl) * S_LEN + cg] = vv;
    }
  }
}

// ---------------- Stage 1b: softmax partials ----------------
__global__ __launch_bounds__(256) void soft_partial_kernel(const float* __restrict__ scores,
                                                           float* __restrict__ part) {
  int h = blockIdx.x, rg = blockIdx.y;
  int tid = threadIdx.x;
  int wave = tid >> 6, lane = tid & 63;
  __shared__ float vs[2048];
  __shared__ float ss[2048];
  __shared__ float red[4];
  int i0 = tid * 8;
#pragma unroll
  for (int e = 0; e < 8; ++e) { vs[i0 + e] = 0.f; ss[i0 + e] = 0.f; }
  for (int rr = 0; rr < 8; ++rr) {
    int r = rg * 8 + rr;
    const float* sp = scores + ((size_t)h * LAST_Q + r) * S_LEN;
    float4 a = *(const float4*)(sp + i0);
    float4 b = *(const float4*)(sp + i0 + 4);
    float x[8] = {a.x, a.y, a.z, a.w, b.x, b.y, b.z, b.w};
    float wm = -1e30f;
#pragma unroll
    for (int e = 0; e < 8; ++e) wm = fmaxf(wm, x[e]);
#pragma unroll
    for (int mk = 1; mk < 64; mk <<= 1) wm = fmaxf(wm, __shfl_xor(wm, mk, 64));
    __syncthreads();
    if (lane == 0) red[wave] = wm;
    __syncthreads();
    float m = fmaxf(fmaxf(red[0], red[1]), fmaxf(red[2], red[3]));
    float psum = 0.f;
#pragma unroll
    for (int e = 0; e < 8; ++e) { x[e] = __expf(x[e] - m); psum += x[e]; }
#pragma unroll
    for (int mk = 1; mk < 64; mk <<= 1) psum += __shfl_xor(psum, mk, 64);
    __syncthreads();
    if (lane == 0) red[wave] = psum;
    __syncthreads();
    float inv = 1.f / (red[0] + red[1] + red[2] + red[3]);
    int rgl = (S_LEN - LAST_Q) + r;
#pragma unroll
    for (int e = 0; e < 8; ++e) {
      float p = x[e] * inv;
      int i = i0 + e;
      vs[i] += p;
      int d = rgl - i;
      if (d >= 0) ss[d] += p;
    }
  }
  __syncthreads();
  float* pb = part + ((size_t)(h * 8 + rg)) * 4096;
#pragma unroll
  for (int e = 0; e < 8; ++e) { pb[i0 + e] = vs[i0 + e]; pb[2048 + i0 + e] = ss[i0 + e]; }
}

// ---------------- Stage 1c: fused reduce + top-k -> bitmasks ----------------
__global__ __launch_bounds__(256) void topk_kernel(const float* __restrict__ part,
                                                   u64* __restrict__ vbits,
                                                   u64* __restrict__ sbits) {
  int h = blockIdx.x;
  int which = blockIdx.y;
  u64* dst = which ? (sbits + h * 32) : (vbits + h * 32);
  u32 K = which ? 512u : 256u;
  int ninf = which ? 64 : 4;
  int tid = threadIdx.x;
  int lane = tid & 63, wid = tid >> 6;
  __shared__ u32 keys[2048];
  __shared__ u32 hist[256];
  __shared__ u32 wpart[4];
  __shared__ u32 sh_pref, sh_kth;
  __shared__ u64 mbw[32];
  int i0 = tid * 8;
  float accv[8] = {0.f, 0.f, 0.f, 0.f, 0.f, 0.f, 0.f, 0.f};
  for (int rg = 0; rg < 8; ++rg) {
    const float* pp = part + ((size_t)(h * 8 + rg)) * 4096 + which * 2048 + i0;
    float4 a = *(const float4*)pp;
    float4 b = *(const float4*)(pp + 4);
    accv[0] += a.x; accv[1] += a.y; accv[2] += a.z; accv[3] += a.w;
    accv[4] += b.x; accv[5] += b.y; accv[6] += b.z; accv[7] += b.w;
  }
#pragma unroll
  for (int e = 0; e < 8; ++e) {
    int i = i0 + e;
    keys[i] = (i < ninf) ? 0x7F800000u : __float_as_uint(accv[e]);
  }
  __syncthreads();
  u32 prefix = 0;
  u32 kth = K;
  for (int shift = 24; shift >= 0; shift -= 8) {
    hist[tid] = 0;
    __syncthreads();
#pragma unroll
    for (int e = 0; e < 8; ++e) {
      u32 kk = keys[i0 + e];
      if (shift == 24 || (kk >> (shift + 8)) == (prefix >> (shift + 8)))
        atomicAdd(&hist[(kk >> shift) & 255], 1u);
    }
    __syncthreads();
    u32 v = hist[tid];
    u32 x = v;
#pragma unroll
    for (int off = 1; off < 64; off <<= 1) {
      u32 o = __shfl_up(x, off, 64);
      if (lane >= off) x += o;
    }
    if (lane == 63) wpart[wid] = x;
    __syncthreads();
    u32 base = 0;
    for (int w2 = 0; w2 < wid; ++w2) base += wpart[w2];
    u32 T = wpart[0] + wpart[1] + wpart[2] + wpart[3];
    u32 Pincl = x + base;
    u32 Sb = T - Pincl + v;
    u32 Sn = T - Pincl;
    if (Sb >= kth && Sn < kth) {
      sh_pref = prefix | ((u32)tid << shift);
      sh_kth = kth - Sn;
    }
    __syncthreads();
    prefix = sh_pref;
    kth = sh_kth;
    __syncthreads();
  }
  u32 t = prefix;
  u32 cnt = 0;
#pragma unroll
  for (int e = 0; e < 8; ++e) cnt += (keys[i0 + e] == t) ? 1u : 0u;
  u32 x = cnt;
#pragma unroll
  for (int off = 1; off < 64; off <<= 1) {
    u32 o = __shfl_up(x, off, 64);
    if (lane >= off) x += o;
  }
  if (lane == 63) wpart[wid] = x;
  __syncthreads();
  u32 base = 0;
  for (int w2 = 0; w2 < wid; ++w2) base += wpart[w2];
  u32 exc = x + base - cnt;
  unsigned char myb = 0;
  u32 seen = 0;
#pragma unroll
  for (int e = 0; e < 8; ++e) {
    u32 kk = keys[i0 + e];
    bool in = (kk > t) || (kk == t && (exc + seen) < kth);
    if (kk == t) ++seen;
    myb |= (in ? 1u : 0u) << e;
  }
  ((unsigned char*)mbw)[tid] = myb;
  __syncthreads();
  if (tid < 32) dst[tid] = mbw[tid];
}

// ---------------- Stage 2: swapped-QK flash attention, pipelined split staging ----------------
// grid 1024, 256 threads (4 waves x 16 q-rows). Head-grouped balanced map: co-CU blocks
// share h; qt set {v,31-v,v+16,15-v} sums 66 tile-units. K/V staged separately with
// counted-vmcnt pipelining (V(t) lands under QK^T, K(t+1) under PV).
template <bool PRE>
__global__ __launch_bounds__(256, 4) void attn_kernel(const float* __restrict__ q,
                                                      const float* __restrict__ kk,
                                                      const float* __restrict__ vv,
                                                      const u16* __restrict__ kpre,
                                                      const u16* __restrict__ vpre,
                                                      const u64* __restrict__ vbits,
                                                      const u64* __restrict__ sbits,
                                                      float* __restrict__ out) {
  int bid = blockIdx.x;
  int u = bid & 255, s = bid >> 8;
  int h = u & 31;
  int v_ = u >> 5;  // 0..7
  int qt;
  switch (s) {
    case 0: qt = v_; break;          // 0..7
    case 1: qt = 31 - v_; break;     // 24..31
    case 2: qt = v_ + 16; break;     // 16..23
    default: qt = 15 - v_; break;    // 8..15
  }
  int tid = threadIdx.x;
  int wave = tid >> 6, lane = tid & 63;
  int grp = lane >> 4, ln = lane & 15;

  __shared__ u16 Ks[8192];
  __shared__ u16 Vt[8192];
  __shared__ u64 smp[34];

  if (tid < 34) smp[tid] = (tid == 0 || tid == 33) ? 0ull : sbits[h * 32 + tid - 1];

  int q0w = qt * 64 + wave * 16;
  // Q fragments, QSCALE folded
  bf16x8 qf[4];
  const float* qrow = q + ((size_t)h * S_LEN + q0w + ln) * D_DIM;
#pragma unroll
  for (int ks = 0; ks < 4; ++ks) {
    const float* p = qrow + ks * 32 + grp * 8;
    float4 a = *(const float4*)p;
    float4 b = *(const float4*)(p + 4);
    bf16x8 f;
    f[0] = (short)f32_bf16(a.x * QSCALE); f[1] = (short)f32_bf16(a.y * QSCALE);
    f[2] = (short)f32_bf16(a.z * QSCALE); f[3] = (short)f32_bf16(a.w * QSCALE);
    f[4] = (short)f32_bf16(b.x * QSCALE); f[5] = (short)f32_bf16(b.y * QSCALE);
    f[6] = (short)f32_bf16(b.z * QSCALE); f[7] = (short)f32_bf16(b.w * QSCALE);
    qf[ks] = f;
  }
  f32x4 of[8];
#pragma unroll
  for (int i = 0; i < 8; ++i) of[i] = (f32x4){0.f, 0.f, 0.f, 0.f};
  float mr = -1e30f;  // per-lane row state (q = q0w + ln), replicated across grp
  float ls = 0.f;

  // hoisted LDS fragment bases (t-invariant, immediate-offset reads in loop)
  const int kb0 = (ln << 7) + (((0 + grp) ^ ln) << 3);
  const int kb1 = (ln << 7) + (((4 + grp) ^ ln) << 3);
  const int kb2 = (ln << 7) + (((8 + grp) ^ ln) << 3);
  const int kb3 = (ln << 7) + (((12 + grp) ^ ln) << 3);
  const int vb0 = (ln << 6) + (((0 + grp) ^ (ln & 7)) << 3);
  const int vb1 = (ln << 6) + (((4 + grp) ^ (ln & 7)) << 3);

  const u16* kp = kpre + (size_t)h * 262144;
  const u16* vp = vpre + (size_t)h * 262144;
  const float* kfb = kk + (size_t)h * S_LEN * D_DIM;
  const float* vfb = vv + (size_t)h * S_LEN * D_DIM;
  const u64* vwp = vbits + h * 32;
  int nt = qt + 1;
  int sb_lane = (lane & 48) + ((lane & 48) >> 2);

  auto dma_k = [&](int t) {
    const u16* ksrc = kp + (size_t)t * 8192;
#pragma unroll
    for (int i = 0; i < 4; ++i) {
      int chunk = wave * 4 + i;
      __builtin_amdgcn_global_load_lds(
          (const __attribute__((address_space(1))) u32*)(const void*)(ksrc + (size_t)(chunk * 64 + lane) * 8),
          (__attribute__((address_space(3))) u32*)(void*)(&Ks[chunk * 512]), 16, 0, 0);
    }
  };
  auto dma_v = [&](int t) {
    const u16* vsrc = vp + (size_t)t * 8192;
#pragma unroll
    for (int i = 0; i < 4; ++i) {
      int chunk = wave * 4 + i;
      __builtin_amdgcn_global_load_lds(
          (const __attribute__((address_space(1))) u32*)(const void*)(vsrc + (size_t)(chunk * 64 + lane) * 8),
          (__attribute__((address_space(3))) u32*)(void*)(&Vt[chunk * 512]), 16, 0, 0);
    }
  };

  if constexpr (PRE) { dma_k(0); dma_v(0); }
  __syncthreads();  // drains prologue DMA + smp writes

  for (int t = 0; t < nt; ++t) {
    int c0 = t * 64;
    if constexpr (!PRE) {
      // fallback: VALU staging of both tiles
      for (int i = tid; i < 512; i += 256) {
        int r = i >> 3, s2 = i & 7;
        const float* srcp = kfb + (size_t)(c0 + r) * D_DIM + s2 * 16;
        float4 f0 = *(const float4*)(srcp);
        float4 f1 = *(const float4*)(srcp + 4);
        float4 f2 = *(const float4*)(srcp + 8);
        float4 f3 = *(const float4*)(srcp + 12);
        bf16x8 t0, t1;
        t0[0] = (short)f32_bf16(f0.x); t0[1] = (short)f32_bf16(f0.y);
        t0[2] = (short)f32_bf16(f0.z); t0[3] = (short)f32_bf16(f0.w);
        t0[4] = (short)f32_bf16(f1.x); t0[5] = (short)f32_bf16(f1.y);
        t0[6] = (short)f32_bf16(f1.z); t0[7] = (short)f32_bf16(f1.w);
        t1[0] = (short)f32_bf16(f2.x); t1[1] = (short)f32_bf16(f2.y);
        t1[2] = (short)f32_bf16(f2.z); t1[3] = (short)f32_bf16(f2.w);
        t1[4] = (short)f32_bf16(f3.x); t1[5] = (short)f32_bf16(f3.y);
        t1[6] = (short)f32_bf16(f3.z); t1[7] = (short)f32_bf16(f3.w);
        int cb0 = s2 * 2, cb1 = s2 * 2 + 1;
        *(bf16x8*)&Ks[r * 128 + ((cb0 ^ (r & 15)) << 3)] = t0;
        *(bf16x8*)&Ks[r * 128 + ((cb1 ^ (r & 15)) << 3)] = t1;
      }
      for (int i = tid; i < 512; i += 256) {
        int r = i >> 3, s2 = i & 7;
        const float* srcp = vfb + (size_t)(c0 + r) * D_DIM + s2 * 16;
#pragma unroll
        for (int x = 0; x < 16; x += 4) {
          float4 f4 = *(const float4*)(srcp + x);
          int d0 = s2 * 16 + x;
          float vals[4] = {f4.x, f4.y, f4.z, f4.w};
#pragma unroll
          for (int y = 0; y < 4; ++y) {
            int d = d0 + y;
            Vt[d * 64 + (((r >> 3) ^ (d & 7)) << 3) + (r & 7)] = f32_bf16(vals[y]);
          }
        }
      }
      __syncthreads();
    }

    // ---- swapped QK^T: sfr[nb][jj] = S[c0+16nb+4grp+jj][q0w+ln] ----
    f32x4 sfr[4];
#pragma unroll
    for (int nb = 0; nb < 4; ++nb) {
      f32x4 acc = (f32x4){0.f, 0.f, 0.f, 0.f};
      acc = __builtin_amdgcn_mfma_f32_16x16x32_bf16(*(const bf16x8*)&Ks[kb0 + nb * 2048], qf[0], acc, 0, 0, 0);
      acc = __builtin_amdgcn_mfma_f32_16x16x32_bf16(*(const bf16x8*)&Ks[kb1 + nb * 2048], qf[1], acc, 0, 0, 0);
      acc = __builtin_amdgcn_mfma_f32_16x16x32_bf16(*(const bf16x8*)&Ks[kb2 + nb * 2048], qf[2], acc, 0, 0, 0);
      acc = __builtin_amdgcn_mfma_f32_16x16x32_bf16(*(const bf16x8*)&Ks[kb3 + nb * 2048], qf[3], acc, 0, 0, 0);
      sfr[nb] = acc;
    }

    // ---- row max ----
    float tm = sfr[0][0];
#pragma unroll
    for (int nb = 0; nb < 4; ++nb)
#pragma unroll
      for (int jj = 0; jj < 4; ++jj) tm = fmaxf(tm, sfr[nb][jj]);
    tm = fmaxf(tm, __shfl_xor(tm, 16, 64));
    tm = fmaxf(tm, __shfl_xor(tm, 32, 64));

    // ---- deferred rescale (T13) ----
    if (__any(tm - mr > RESCALE_THR)) {
      float mn = fmaxf(mr, tm);
      float ex = __builtin_amdgcn_exp2f(mr - mn);
      mr = mn;
      ls *= ex;
      float e0 = __shfl(ex, sb_lane, 64);
      float e1 = __shfl(ex, sb_lane + 1, 64);
      float e2 = __shfl(ex, sb_lane + 2, 64);
      float e3 = __shfl(ex, sb_lane + 3, 64);
#pragma unroll
      for (int db = 0; db < 8; ++db) {
        of[db][0] *= e0; of[db][1] *= e1; of[db][2] *= e2; of[db][3] *= e3;
      }
    }

    // ---- mask + p = exp2 + pack ----
    int Cb = (q0w + ln) - c0 - (grp << 2);
    float rs = 0.f;
    u32 pkw[8];
    if (c0 >= q0w - 48) {
#pragma unroll
      for (int nb = 0; nb < 4; ++nb) {
        float pv[4];
#pragma unroll
        for (int jj = 0; jj < 4; ++jj) {
          bool keep = (16 * nb + jj) <= Cb;
          float p = keep ? __builtin_amdgcn_exp2f(sfr[nb][jj] - mr) : 0.f;
          rs += p;
          pv[jj] = p;
        }
        pkw[nb * 2] = cvt_pk_bf16(pv[0], pv[1]);
        pkw[nb * 2 + 1] = cvt_pk_bf16(pv[2], pv[3]);
      }
    } else {
      int b0 = Cb - 63;
      int w0i = (b0 >> 6) + 1;
      int sh = b0 & 63;
      u64 lo = smp[w0i];
      u64 hi = smp[w0i + 1];
      u64 W = (sh == 0) ? lo : ((lo >> sh) | (hi << (64 - sh)));
      u64 vword = vwp[t];
#pragma unroll
      for (int nb = 0; nb < 4; ++nb) {
        u32 vn = (u32)(vword >> (16 * nb + 4 * grp)) & 0xFu;
        u32 sn = (u32)(W >> (60 - 16 * nb)) & 0xFu;
        float pv[4];
#pragma unroll
        for (int jj = 0; jj < 4; ++jj) {
          u32 keep = ((vn >> jj) | (sn >> (3 - jj))) & 1u;
          float p = keep ? __builtin_amdgcn_exp2f(sfr[nb][jj] - mr) : 0.f;
          rs += p;
          pv[jj] = p;
        }
        pkw[nb * 2] = cvt_pk_bf16(pv[0], pv[1]);
        pkw[nb * 2 + 1] = cvt_pk_bf16(pv[2], pv[3]);
      }
    }
    rs += __shfl_xor(rs, 16, 64);
    rs += __shfl_xor(rs, 32, 64);
    ls += rs;

    // ---- BAR_A: Ks reads done + V(t) visible; then prefetch K(t+1) ----
    if constexpr (PRE) {
      __builtin_amdgcn_sched_barrier(0);
      asm volatile("s_waitcnt vmcnt(0)" ::: "memory");  // V(t) landed (only outstanding)
      __builtin_amdgcn_s_barrier();
      if (t + 1 < nt) dma_k(t + 1);
    }

    // ---- PV: pa via shfl of packed P ----
#pragma unroll
    for (int ks2 = 0; ks2 < 2; ++ks2) {
      int sl0 = ln + ((lane & 16) << 1);
      int sl1 = sl0 + 16;
      u32 a0 = __shfl(pkw[ks2 * 4 + 0], sl0, 64);
      u32 a1 = __shfl(pkw[ks2 * 4 + 1], sl0, 64);
      u32 a2 = __shfl(pkw[ks2 * 4 + 0], sl1, 64);
      u32 a3 = __shfl(pkw[ks2 * 4 + 1], sl1, 64);
      u32 b0_ = __shfl(pkw[ks2 * 4 + 2], sl0, 64);
      u32 b1_ = __shfl(pkw[ks2 * 4 + 3], sl0, 64);
      u32 b2_ = __shfl(pkw[ks2 * 4 + 2], sl1, 64);
      u32 b3_ = __shfl(pkw[ks2 * 4 + 3], sl1, 64);
      bool hi2 = grp >= 2;
      union { u32 w[4]; bf16x8 v; } pu;
      pu.w[0] = hi2 ? b0_ : a0;
      pu.w[1] = hi2 ? b1_ : a1;
      pu.w[2] = hi2 ? b2_ : a2;
      pu.w[3] = hi2 ? b3_ : a3;
      int vb = ks2 ? vb1 : vb0;
#pragma unroll
      for (int db = 0; db < 8; ++db) {
        bf16x8 vf = *(const bf16x8*)&Vt[vb + db * 1024];
        of[db] = __builtin_amdgcn_mfma_f32_16x16x32_bf16(pu.v, vf, of[db], 0, 0, 0);
      }
    }

    // ---- BAR_B: Vt reads done; prefetch V(t+1); BAR_C: K(t+1) visible ----
    if constexpr (PRE) {
      __builtin_amdgcn_sched_barrier(0);
      __builtin_amdgcn_s_barrier();
      if (t + 1 < nt) {
        dma_v(t + 1);
        asm volatile("s_waitcnt vmcnt(4)" ::: "memory");  // K(t+1) landed (oldest 4 of 8)
      }
      __builtin_amdgcn_s_barrier();
    } else {
      __syncthreads();
    }
  }

  // ---- epilogue ----
  float invl = 1.f / ls;
  float i0 = __shfl(invl, sb_lane, 64);
  float i1 = __shfl(invl, sb_lane + 1, 64);
  float i2 = __shfl(invl, sb_lane + 2, 64);
  float i3 = __shfl(invl, sb_lane + 3, 64);
  float* ob = out + ((size_t)h * S_LEN + q0w) * D_DIM;
#pragma unroll
  for (int db = 0; db < 8; ++db) {
    ob[(size_t)(grp * 4 + 0) * D_DIM + db * 16 + ln] = of[db][0] * i0;
    ob[(size_t)(grp * 4 + 1) * D_DIM + db * 16 + ln] = of[db][1] * i1;
    ob[(size_t)(grp * 4 + 2) * D_DIM + db * 16 + ln] = of[db][2] * i2;
    ob[(size_t)(grp * 4 + 3) * D_DIM + db * 16 + ln] = of[db][3] * i3;
  }
}

extern "C" void kernel_launch(void* const* d_in, const int* in_sizes, int n_in,
                              void* d_out, int out_size, void* d_ws, size_t ws_size,
                              hipStream_t stream) {
  const float* q = (const float*)d_in[0];
  const float* k = (const float*)d_in[1];
  const float* v = (const float*)d_in[2];
  float* out = (float*)d_out;
  float* scores = out;
  float* part = out + 4194304;
  u64* vbits = (u64*)d_ws;
  u64* sbits = vbits + 1024;
  const size_t PRE_NEED = 16384 + 2ull * 16777216;
  bool pre = ws_size >= PRE_NEED;
  u16* kpre = (u16*)((char*)d_ws + 16384);
  u16* vpre = kpre + 8388608;

  if (pre) conv_kernel<<<1024, 256, 0, stream>>>(k, v, kpre, vpre);
  est_kernel<<<dim3(32, 32), 256, 0, stream>>>(q, k, scores);
  soft_partial_kernel<<<dim3(32, 8), 256, 0, stream>>>(scores, part);
  topk_kernel<<<dim3(32, 2), 256, 0, stream>>>(part, vbits, sbits);
  if (pre)
    attn_kernel<true><<<1024, 256, 0, stream>>>(q, k, v, kpre, vpre, vbits, sbits, out);
  else
    attn_kernel<false><<<1024, 256, 0, stream>>>(q, k, v, kpre, vpre, vbits, sbits, out);
}